// Round 2
// baseline (5549.270 us; speedup 1.0000x reference)
//
#include <hip/hip_runtime.h>
#include <math.h>

#define N_NODES 20000
#define N_EDGES 320000
#define N_GRAPHS 64
#define D_IN 1280
#define D_H 512
#define D_FC 1024
#define OUT_DIMS 5000

// ---------------- fp32 tiled GEMM: C[M,N] = A[M,K] @ B[K,N] ----------------
// 64x64 tile per 256-thread block, 4x4 per thread, BK=16. K must be %16.
__global__ __launch_bounds__(256) void gemm_tile(const float* __restrict__ A,
                                                 const float* __restrict__ B,
                                                 float* __restrict__ C,
                                                 int M, int N, int K) {
    __shared__ float As[16][64];
    __shared__ float Bs[16][64];
    const int t = threadIdx.x;
    const int tx = t & 15, ty = t >> 4;
    const int rowBase = blockIdx.y * 64;
    const int colBase = blockIdx.x * 64;
    float acc[4][4] = {};
    for (int k0 = 0; k0 < K; k0 += 16) {
#pragma unroll
        for (int i = 0; i < 4; ++i) {          // A tile 64x16 -> As[kk][row]
            int idx = t + i * 256;
            int row = idx >> 4, kk = idx & 15;
            int gr = rowBase + row;
            As[kk][row] = (gr < M) ? A[(size_t)gr * K + k0 + kk] : 0.f;
        }
#pragma unroll
        for (int i = 0; i < 4; ++i) {          // B tile 16x64 -> Bs[kk][col]
            int idx = t + i * 256;
            int kk = idx >> 6, col = idx & 63;
            int gc = colBase + col;
            Bs[kk][col] = (gc < N) ? B[(size_t)(k0 + kk) * N + gc] : 0.f;
        }
        __syncthreads();
#pragma unroll
        for (int kk = 0; kk < 16; ++kk) {
            float a[4], b[4];
#pragma unroll
            for (int i = 0; i < 4; ++i) a[i] = As[kk][ty * 4 + i];
#pragma unroll
            for (int j = 0; j < 4; ++j) b[j] = Bs[kk][tx * 4 + j];
#pragma unroll
            for (int i = 0; i < 4; ++i)
#pragma unroll
                for (int j = 0; j < 4; ++j) acc[i][j] = fmaf(a[i], b[j], acc[i][j]);
        }
        __syncthreads();
    }
#pragma unroll
    for (int i = 0; i < 4; ++i) {
        int gr = rowBase + ty * 4 + i;
        if (gr >= M) continue;
#pragma unroll
        for (int j = 0; j < 4; ++j) {
            int gc = colBase + tx * 4 + j;
            if (gc < N) C[(size_t)gr * N + gc] = acc[i][j];
        }
    }
}

// ---------------- graph kernels ----------------
__global__ void count_deg(const int* __restrict__ dst, float* __restrict__ deg) {
    int e = blockIdx.x * blockDim.x + threadIdx.x;
    if (e < N_EDGES) atomicAdd(deg + dst[e], 1.0f);
}

__global__ void compute_dinv(const float* __restrict__ deg, float* __restrict__ dinv) {
    int v = blockIdx.x * blockDim.x + threadIdx.x;
    if (v < N_NODES) dinv[v] = 1.0f / sqrtf(deg[v] + 1.0f);  // +1 self-loop
}

// 128 threads per edge, 4 contiguous feats each: A[dst] += H[src]*coef
__global__ void scatter_edges(const float* __restrict__ H, float* __restrict__ Aagg,
                              const int* __restrict__ src,
                              const int* __restrict__ dst,
                              const float* __restrict__ dinv) {
    int tid = blockIdx.x * blockDim.x + threadIdx.x;
    int e = tid >> 7;
    if (e >= N_EDGES) return;
    int f = (tid & 127) * 4;
    int s = src[e], d = dst[e];
    float coef = dinv[s] * dinv[d];
    float4 h = *(const float4*)(H + (size_t)s * D_H + f);
    float* o = Aagg + (size_t)d * D_H + f;
    atomicAdd(o + 0, h.x * coef);
    atomicAdd(o + 1, h.y * coef);
    atomicAdd(o + 2, h.z * coef);
    atomicAdd(o + 3, h.w * coef);
}

// out = relu(Aagg + H*dinv^2 + bias)   (out may alias Aagg: same-element RMW)
__global__ void finalize_relu(const float* __restrict__ Aagg, const float* __restrict__ H,
                              const float* __restrict__ dinv, const float* __restrict__ bias,
                              float* __restrict__ out) {
    int tid = blockIdx.x * blockDim.x + threadIdx.x;
    int v = tid >> 7;
    if (v >= N_NODES) return;
    int f = (tid & 127) * 4;
    float di = dinv[v];
    float sl = di * di;
    float4 a = *(const float4*)(Aagg + (size_t)v * D_H + f);
    float4 h = *(const float4*)(H + (size_t)v * D_H + f);
    float4 b = *(const float4*)(bias + f);
    float4 r;
    r.x = fmaxf(a.x + h.x * sl + b.x, 0.f);
    r.y = fmaxf(a.y + h.y * sl + b.y, 0.f);
    r.z = fmaxf(a.z + h.z * sl + b.z, 0.f);
    r.w = fmaxf(a.w + h.w * sl + b.w, 0.f);
    *(float4*)(out + (size_t)v * D_H + f) = r;
}

// global max pool; values are post-ReLU (>=0) so int-ordered atomicMax is valid, g init 0
__global__ void pool_max(const float* __restrict__ h, const int* __restrict__ batch,
                         float* __restrict__ g) {
    int tid = blockIdx.x * blockDim.x + threadIdx.x;
    int v = tid >> 7;
    if (v >= N_NODES) return;
    int f = (tid & 127) * 4;
    int gr = batch[v];
    float4 x = *(const float4*)(h + (size_t)v * D_H + f);
    int* o = (int*)(g + (size_t)gr * D_H + f);
    atomicMax(o + 0, __float_as_int(x.x));
    atomicMax(o + 1, __float_as_int(x.y));
    atomicMax(o + 2, __float_as_int(x.z));
    atomicMax(o + 3, __float_as_int(x.w));
}

__global__ void bias_relu(float* __restrict__ x, const float* __restrict__ b, int total, int N) {
    int i = blockIdx.x * blockDim.x + threadIdx.x;
    if (i < total) x[i] = fmaxf(x[i] + b[i % N], 0.f);
}

__global__ void bn_sigmoid(const float* __restrict__ logits, const float* __restrict__ b2,
                           const float* __restrict__ gamma, const float* __restrict__ beta,
                           float* __restrict__ out) {
    int i = blockIdx.x * blockDim.x + threadIdx.x;
    if (i >= N_GRAPHS * OUT_DIMS) return;
    int c = i % OUT_DIMS;
    const float s = 0.9999950000374997f;  // 1/sqrt(1+1e-5)
    float z = (logits[i] + b2[c]) * (gamma[c] * s) + beta[c];
    out[i] = 1.f / (1.f + expf(-z));
}

extern "C" void kernel_launch(void* const* d_in, const int* in_sizes, int n_in,
                              void* d_out, int out_size, void* d_ws, size_t ws_size,
                              hipStream_t stream) {
    const float* x     = (const float*)d_in[0];
    const int*   ei    = (const int*)d_in[1];    // int64 in reference -> int32 on device
    const int*   batch = (const int*)d_in[2];
    const float* Wg1   = (const float*)d_in[3];
    const float* bg1   = (const float*)d_in[4];
    const float* Wg2   = (const float*)d_in[5];
    const float* bg2   = (const float*)d_in[6];
    const float* W1    = (const float*)d_in[7];
    const float* b1    = (const float*)d_in[8];
    const float* W2    = (const float*)d_in[9];
    const float* b2    = (const float*)d_in[10];
    const float* gamma = (const float*)d_in[11];
    const float* beta  = (const float*)d_in[12];
    const int* src = ei;
    const int* dst = ei + N_EDGES;
    float* out = (float*)d_out;

    float* bufA   = (float*)d_ws;                       // [N_NODES, D_H]
    float* bufB   = bufA + (size_t)N_NODES * D_H;       // [N_NODES, D_H]
    float* deg    = bufB + (size_t)N_NODES * D_H;       // [N_NODES]
    float* dinv   = deg + N_NODES;                      // [N_NODES]
    float* gbuf   = dinv + N_NODES;                     // [N_GRAPHS, D_H]
    float* fc1o   = gbuf + N_GRAPHS * D_H;              // [N_GRAPHS, D_FC]
    float* logits = fc1o + N_GRAPHS * D_FC;             // [N_GRAPHS, OUT_DIMS]

    const int NB_NODE = (N_NODES * 128 + 255) / 256;    // node x feat4 kernels
    const int NB_EDGE = (N_EDGES * 128 + 255) / 256;    // edge x feat4 kernels

    // degree / dinv
    hipMemsetAsync(deg, 0, N_NODES * sizeof(float), stream);
    count_deg<<<(N_EDGES + 255) / 256, 256, 0, stream>>>(dst, deg);
    compute_dinv<<<(N_NODES + 255) / 256, 256, 0, stream>>>(deg, dinv);

    dim3 gconv((D_H + 63) / 64, (N_NODES + 63) / 64);

    // conv1: H = x @ Wg1 ; agg ; relu  -> bufB
    gemm_tile<<<gconv, 256, 0, stream>>>(x, Wg1, bufA, N_NODES, D_H, D_IN);
    hipMemsetAsync(bufB, 0, (size_t)N_NODES * D_H * sizeof(float), stream);
    scatter_edges<<<NB_EDGE, 256, 0, stream>>>(bufA, bufB, src, dst, dinv);
    finalize_relu<<<NB_NODE, 256, 0, stream>>>(bufB, bufA, dinv, bg1, bufB);

    // conv2: H2 = h1 @ Wg2 ; agg ; relu -> bufB
    gemm_tile<<<gconv, 256, 0, stream>>>(bufB, Wg2, bufA, N_NODES, D_H, D_H);
    hipMemsetAsync(bufB, 0, (size_t)N_NODES * D_H * sizeof(float), stream);
    scatter_edges<<<NB_EDGE, 256, 0, stream>>>(bufA, bufB, src, dst, dinv);
    finalize_relu<<<NB_NODE, 256, 0, stream>>>(bufB, bufA, dinv, bg2, bufB);

    // global max pool -> gbuf [64, 512]
    hipMemsetAsync(gbuf, 0, N_GRAPHS * D_H * sizeof(float), stream);
    pool_max<<<NB_NODE, 256, 0, stream>>>(bufB, batch, gbuf);

    // fc1: [64,512]@[512,1024] + b1, relu
    dim3 gfc1((D_FC + 63) / 64, (N_GRAPHS + 63) / 64);
    gemm_tile<<<gfc1, 256, 0, stream>>>(gbuf, W1, fc1o, N_GRAPHS, D_FC, D_H);
    bias_relu<<<(N_GRAPHS * D_FC + 255) / 256, 256, 0, stream>>>(fc1o, b1, N_GRAPHS * D_FC, D_FC);

    // fc2: [64,1024]@[1024,5000] -> logits ; BN + sigmoid -> out
    dim3 gfc2((OUT_DIMS + 63) / 64, (N_GRAPHS + 63) / 64);
    gemm_tile<<<gfc2, 256, 0, stream>>>(fc1o, W2, logits, N_GRAPHS, OUT_DIMS, D_FC);
    bn_sigmoid<<<(N_GRAPHS * OUT_DIMS + 255) / 256, 256, 0, stream>>>(logits, b2, gamma, beta, out);
}

// Round 3
// 1484.265 us; speedup vs baseline: 3.7387x; 3.7387x over previous
//
#include <hip/hip_runtime.h>
#include <math.h>

#define N_NODES 20000
#define N_EDGES 320000
#define N_GRAPHS 64
#define D_IN 1280
#define D_H 512
#define D_FC 1024
#define OUT_DIMS 5000

// ---------------- fp32 tiled GEMM: C[M,N] = A[M,K] @ B[K,N] ----------------
// 64x64 tile per 256-thread block, 4x4 per thread, BK=16. K must be %16.
__global__ __launch_bounds__(256) void gemm_tile(const float* __restrict__ A,
                                                 const float* __restrict__ B,
                                                 float* __restrict__ C,
                                                 int M, int N, int K) {
    __shared__ float As[16][64];
    __shared__ float Bs[16][64];
    const int t = threadIdx.x;
    const int tx = t & 15, ty = t >> 4;
    const int rowBase = blockIdx.y * 64;
    const int colBase = blockIdx.x * 64;
    float acc[4][4] = {};
    for (int k0 = 0; k0 < K; k0 += 16) {
#pragma unroll
        for (int i = 0; i < 4; ++i) {          // A tile 64x16 -> As[kk][row]
            int idx = t + i * 256;
            int row = idx >> 4, kk = idx & 15;
            int gr = rowBase + row;
            As[kk][row] = (gr < M) ? A[(size_t)gr * K + k0 + kk] : 0.f;
        }
#pragma unroll
        for (int i = 0; i < 4; ++i) {          // B tile 16x64 -> Bs[kk][col]
            int idx = t + i * 256;
            int kk = idx >> 6, col = idx & 63;
            int gc = colBase + col;
            Bs[kk][col] = (gc < N) ? B[(size_t)(k0 + kk) * N + gc] : 0.f;
        }
        __syncthreads();
#pragma unroll
        for (int kk = 0; kk < 16; ++kk) {
            float a[4], b[4];
#pragma unroll
            for (int i = 0; i < 4; ++i) a[i] = As[kk][ty * 4 + i];
#pragma unroll
            for (int j = 0; j < 4; ++j) b[j] = Bs[kk][tx * 4 + j];
#pragma unroll
            for (int i = 0; i < 4; ++i)
#pragma unroll
                for (int j = 0; j < 4; ++j) acc[i][j] = fmaf(a[i], b[j], acc[i][j]);
        }
        __syncthreads();
    }
#pragma unroll
    for (int i = 0; i < 4; ++i) {
        int gr = rowBase + ty * 4 + i;
        if (gr >= M) continue;
#pragma unroll
        for (int j = 0; j < 4; ++j) {
            int gc = colBase + tx * 4 + j;
            if (gc < N) C[(size_t)gr * N + gc] = acc[i][j];
        }
    }
}

// ---------------- CSR construction ----------------
__global__ void hist_deg(const int* __restrict__ dst, int* __restrict__ cnt) {
    int e = blockIdx.x * blockDim.x + threadIdx.x;
    if (e < N_EDGES) atomicAdd(cnt + dst[e], 1);
}

__global__ void compute_dinv(const int* __restrict__ cnt, float* __restrict__ dinv) {
    int v = blockIdx.x * blockDim.x + threadIdx.x;
    if (v < N_NODES) dinv[v] = rsqrtf((float)cnt[v] + 1.0f);  // +1 self-loop
}

// single-block exclusive scan of cnt[N_NODES] -> rowptr[N_NODES+1]
__global__ __launch_bounds__(256) void scan_rowptr(const int* __restrict__ cnt,
                                                   int* __restrict__ rowptr) {
    __shared__ int sums[256];
    const int t = threadIdx.x;
    const int CH = (N_NODES + 255) / 256;  // 79
    const int base = t * CH;
    int s = 0;
    for (int i = 0; i < CH; ++i) {
        int v = base + i;
        if (v < N_NODES) s += cnt[v];
    }
    sums[t] = s;
    __syncthreads();
    // Hillis-Steele inclusive scan over 256 partials
    for (int off = 1; off < 256; off <<= 1) {
        int y = (t >= off) ? sums[t - off] : 0;
        __syncthreads();
        sums[t] += y;
        __syncthreads();
    }
    int run = sums[t] - s;  // exclusive prefix for this chunk
    for (int i = 0; i < CH; ++i) {
        int v = base + i;
        if (v < N_NODES) {
            rowptr[v] = run;
            run += cnt[v];
        }
    }
    if (t == 255) rowptr[N_NODES] = run;
}

__global__ void fill_csr(const int* __restrict__ src, const int* __restrict__ dst,
                         const int* __restrict__ rowptr, int* __restrict__ cursor,
                         int* __restrict__ col) {
    int e = blockIdx.x * blockDim.x + threadIdx.x;
    if (e < N_EDGES) {
        int d = dst[e];
        int p = rowptr[d] + atomicAdd(cursor + d, 1);
        col[p] = src[e];
    }
}

// ---------------- CSR gather-aggregate, fused self-loop + bias + ReLU ----------------
// one 128-thread block per dst node; thread f covers feats [4f, 4f+4)
__global__ __launch_bounds__(128) void gather_agg_relu(const float* __restrict__ H,
                                                       const int* __restrict__ rowptr,
                                                       const int* __restrict__ col,
                                                       const float* __restrict__ dinv,
                                                       const float* __restrict__ bias,
                                                       float* __restrict__ out) {
    const int v = blockIdx.x;
    const int f = threadIdx.x * 4;
    const int beg = rowptr[v], end = rowptr[v + 1];
    const float dv = dinv[v];
    float4 acc = {0.f, 0.f, 0.f, 0.f};
    int j = beg;
    // 2-way unroll for load-latency overlap
    for (; j + 1 < end; j += 2) {
        int s0 = col[j], s1 = col[j + 1];
        float c0 = dinv[s0] * dv, c1 = dinv[s1] * dv;
        float4 h0 = *(const float4*)(H + (size_t)s0 * D_H + f);
        float4 h1 = *(const float4*)(H + (size_t)s1 * D_H + f);
        acc.x += h0.x * c0 + h1.x * c1;
        acc.y += h0.y * c0 + h1.y * c1;
        acc.z += h0.z * c0 + h1.z * c1;
        acc.w += h0.w * c0 + h1.w * c1;
    }
    if (j < end) {
        int s0 = col[j];
        float c0 = dinv[s0] * dv;
        float4 h0 = *(const float4*)(H + (size_t)s0 * D_H + f);
        acc.x += h0.x * c0;
        acc.y += h0.y * c0;
        acc.z += h0.z * c0;
        acc.w += h0.w * c0;
    }
    const float sl = dv * dv;
    float4 hv = *(const float4*)(H + (size_t)v * D_H + f);
    float4 b = *(const float4*)(bias + f);
    float4 r;
    r.x = fmaxf(acc.x + hv.x * sl + b.x, 0.f);
    r.y = fmaxf(acc.y + hv.y * sl + b.y, 0.f);
    r.z = fmaxf(acc.z + hv.z * sl + b.z, 0.f);
    r.w = fmaxf(acc.w + hv.w * sl + b.w, 0.f);
    *(float4*)(out + (size_t)v * D_H + f) = r;
}

// global max pool; values are post-ReLU (>=0) so int-ordered atomicMax is valid, g init 0
__global__ void pool_max(const float* __restrict__ h, const int* __restrict__ batch,
                         float* __restrict__ g) {
    int tid = blockIdx.x * blockDim.x + threadIdx.x;
    int v = tid >> 7;
    if (v >= N_NODES) return;
    int f = (tid & 127) * 4;
    int gr = batch[v];
    float4 x = *(const float4*)(h + (size_t)v * D_H + f);
    int* o = (int*)(g + (size_t)gr * D_H + f);
    atomicMax(o + 0, __float_as_int(x.x));
    atomicMax(o + 1, __float_as_int(x.y));
    atomicMax(o + 2, __float_as_int(x.z));
    atomicMax(o + 3, __float_as_int(x.w));
}

__global__ void bias_relu(float* __restrict__ x, const float* __restrict__ b, int total, int N) {
    int i = blockIdx.x * blockDim.x + threadIdx.x;
    if (i < total) x[i] = fmaxf(x[i] + b[i % N], 0.f);
}

__global__ void bn_sigmoid(const float* __restrict__ logits, const float* __restrict__ b2,
                           const float* __restrict__ gamma, const float* __restrict__ beta,
                           float* __restrict__ out) {
    int i = blockIdx.x * blockDim.x + threadIdx.x;
    if (i >= N_GRAPHS * OUT_DIMS) return;
    int c = i % OUT_DIMS;
    const float s = 0.9999950000374997f;  // 1/sqrt(1+1e-5)
    float z = (logits[i] + b2[c]) * (gamma[c] * s) + beta[c];
    out[i] = 1.f / (1.f + expf(-z));
}

extern "C" void kernel_launch(void* const* d_in, const int* in_sizes, int n_in,
                              void* d_out, int out_size, void* d_ws, size_t ws_size,
                              hipStream_t stream) {
    const float* x     = (const float*)d_in[0];
    const int*   ei    = (const int*)d_in[1];    // int64 in reference -> int32 on device
    const int*   batch = (const int*)d_in[2];
    const float* Wg1   = (const float*)d_in[3];
    const float* bg1   = (const float*)d_in[4];
    const float* Wg2   = (const float*)d_in[5];
    const float* bg2   = (const float*)d_in[6];
    const float* W1    = (const float*)d_in[7];
    const float* b1    = (const float*)d_in[8];
    const float* W2    = (const float*)d_in[9];
    const float* b2    = (const float*)d_in[10];
    const float* gamma = (const float*)d_in[11];
    const float* beta  = (const float*)d_in[12];
    const int* src = ei;
    const int* dst = ei + N_EDGES;
    float* out = (float*)d_out;

    float* bufA   = (float*)d_ws;                       // [N_NODES, D_H]
    float* bufB   = bufA + (size_t)N_NODES * D_H;       // [N_NODES, D_H]
    float* dinv   = bufB + (size_t)N_NODES * D_H;       // [N_NODES]
    float* gbuf   = dinv + N_NODES;                     // [N_GRAPHS, D_H]
    float* fc1o   = gbuf + N_GRAPHS * D_H;              // [N_GRAPHS, D_FC]
    float* logits = fc1o + N_GRAPHS * D_FC;             // [N_GRAPHS, OUT_DIMS]
    int*   cnt    = (int*)(logits + N_GRAPHS * OUT_DIMS);  // [N_NODES]
    int*   rowptr = cnt + N_NODES;                      // [N_NODES+1]
    int*   cursor = rowptr + N_NODES + 1;               // [N_NODES]
    int*   colidx = cursor + N_NODES;                   // [N_EDGES]

    const int NB_NODE = (N_NODES * 128 + 255) / 256;    // node x feat4 kernels

    // ---- CSR build (by dst) + dinv ----
    hipMemsetAsync(cnt, 0, N_NODES * sizeof(int), stream);
    hipMemsetAsync(cursor, 0, N_NODES * sizeof(int), stream);
    hist_deg<<<(N_EDGES + 255) / 256, 256, 0, stream>>>(dst, cnt);
    compute_dinv<<<(N_NODES + 255) / 256, 256, 0, stream>>>(cnt, dinv);
    scan_rowptr<<<1, 256, 0, stream>>>(cnt, rowptr);
    fill_csr<<<(N_EDGES + 255) / 256, 256, 0, stream>>>(src, dst, rowptr, cursor, colidx);

    dim3 gconv((D_H + 63) / 64, (N_NODES + 63) / 64);

    // conv1: H = x @ Wg1 ; gather-agg + relu -> bufB
    gemm_tile<<<gconv, 256, 0, stream>>>(x, Wg1, bufA, N_NODES, D_H, D_IN);
    gather_agg_relu<<<N_NODES, 128, 0, stream>>>(bufA, rowptr, colidx, dinv, bg1, bufB);

    // conv2: H2 = h1 @ Wg2 ; gather-agg + relu -> bufB
    gemm_tile<<<gconv, 256, 0, stream>>>(bufB, Wg2, bufA, N_NODES, D_H, D_H);
    gather_agg_relu<<<N_NODES, 128, 0, stream>>>(bufA, rowptr, colidx, dinv, bg2, bufB);

    // global max pool -> gbuf [64, 512]
    hipMemsetAsync(gbuf, 0, N_GRAPHS * D_H * sizeof(float), stream);
    pool_max<<<NB_NODE, 256, 0, stream>>>(bufB, batch, gbuf);

    // fc1: [64,512]@[512,1024] + b1, relu
    dim3 gfc1((D_FC + 63) / 64, (N_GRAPHS + 63) / 64);
    gemm_tile<<<gfc1, 256, 0, stream>>>(gbuf, W1, fc1o, N_GRAPHS, D_FC, D_H);
    bias_relu<<<(N_GRAPHS * D_FC + 255) / 256, 256, 0, stream>>>(fc1o, b1, N_GRAPHS * D_FC, D_FC);

    // fc2: [64,1024]@[1024,5000] -> logits ; BN + sigmoid -> out
    dim3 gfc2((OUT_DIMS + 63) / 64, (N_GRAPHS + 63) / 64);
    gemm_tile<<<gfc2, 256, 0, stream>>>(fc1o, W2, logits, N_GRAPHS, OUT_DIMS, D_FC);
    bn_sigmoid<<<(N_GRAPHS * OUT_DIMS + 255) / 256, 256, 0, stream>>>(logits, b2, gamma, beta, out);
}

// Round 4
// 866.777 us; speedup vs baseline: 6.4022x; 1.7124x over previous
//
#include <hip/hip_runtime.h>
#include <math.h>

#define N_NODES 20000
#define N_EDGES 320000
#define N_GRAPHS 64
#define D_IN 1280
#define D_H 512
#define D_FC 1024
#define OUT_DIMS 5000

typedef unsigned short ushort_t;
typedef short bf16x8 __attribute__((ext_vector_type(8)));
typedef float f32x4 __attribute__((ext_vector_type(4)));

__device__ __forceinline__ ushort_t f2b(float x) {
    unsigned u = __float_as_uint(x);
    unsigned r = (u + 0x7FFFu + ((u >> 16) & 1u)) >> 16;  // RNE
    return (ushort_t)r;
}

// ============ bf16 MFMA GEMM: C[M,N] = A[M,K] @ BT[N,K]^T ============
// 128x128 block tile, 4 waves, 64x64/wave as 4x4 grid of 16x16x32 MFMA.
// LDS tiles stored [dim][k] with k contiguous, row stride 40 shorts (80 B,
// pad +8 bf16 -> 2-way bank aliasing only, which is free).
// A_IS_F32: stage fp32 A with inline bf16 conversion; else A is bf16.
template <bool A_IS_F32>
__global__ __launch_bounds__(256) void mfma_gemm(const void* __restrict__ Ap,
                                                 const ushort_t* __restrict__ BT,
                                                 float* __restrict__ C,
                                                 int M, int N, int K) {
    __shared__ ushort_t As[128 * 40];
    __shared__ ushort_t Bs[128 * 40];
    const int t = threadIdx.x;
    const int lane = t & 63, wave = t >> 6;
    const int wrow = (wave >> 1) * 64, wcol = (wave & 1) * 64;
    const int lo = lane & 15, quad = lane >> 4;
    const int rowBase = blockIdx.y * 128;
    const int colBase = blockIdx.x * 128;

    f32x4 acc[4][4] = {};

    for (int k0 = 0; k0 < K; k0 += 32) {
        __syncthreads();  // previous iteration's LDS reads complete
#pragma unroll
        for (int i = 0; i < 2; ++i) {  // stage A: 512 slots of 8 bf16
            int s = t + i * 256;
            int r = s >> 2, c8 = (s & 3) * 8;
            int gr = rowBase + r;
            ushort_t* dp = &As[r * 40 + c8];
            if (A_IS_F32) {
                const float* A = (const float*)Ap;
                float4 v0 = {0.f, 0.f, 0.f, 0.f}, v1 = {0.f, 0.f, 0.f, 0.f};
                if (gr < M) {
                    const float* p = A + (size_t)gr * K + k0 + c8;
                    v0 = *(const float4*)p;
                    v1 = *(const float4*)(p + 4);
                }
                ushort_t w[8] = {f2b(v0.x), f2b(v0.y), f2b(v0.z), f2b(v0.w),
                                 f2b(v1.x), f2b(v1.y), f2b(v1.z), f2b(v1.w)};
                *(uint4*)dp = *(uint4*)w;
            } else {
                const ushort_t* A = (const ushort_t*)Ap;
                uint4 v = {0u, 0u, 0u, 0u};
                if (gr < M) v = *(const uint4*)(A + (size_t)gr * K + k0 + c8);
                *(uint4*)dp = v;
            }
        }
#pragma unroll
        for (int i = 0; i < 2; ++i) {  // stage B (bf16, pre-transposed)
            int s = t + i * 256;
            int n = s >> 2, c8 = (s & 3) * 8;
            int gc = colBase + n;
            uint4 v = {0u, 0u, 0u, 0u};
            if (gc < N) v = *(const uint4*)(BT + (size_t)gc * K + k0 + c8);
            *(uint4*)&Bs[n * 40 + c8] = v;
        }
        __syncthreads();
        // frags: lane holds A[m=lo][k=quad*8+j], B[k=quad*8+j][n=lo]
        bf16x8 af[4], bfr[4];
#pragma unroll
        for (int i = 0; i < 4; ++i)
            af[i] = *(const bf16x8*)&As[(wrow + i * 16 + lo) * 40 + quad * 8];
#pragma unroll
        for (int j = 0; j < 4; ++j)
            bfr[j] = *(const bf16x8*)&Bs[(wcol + j * 16 + lo) * 40 + quad * 8];
#pragma unroll
        for (int i = 0; i < 4; ++i)
#pragma unroll
            for (int j = 0; j < 4; ++j)
                acc[i][j] = __builtin_amdgcn_mfma_f32_16x16x32_bf16(af[i], bfr[j], acc[i][j], 0, 0, 0);
    }
    // epilogue: C/D layout col=lane&15, row=quad*4+reg
#pragma unroll
    for (int i = 0; i < 4; ++i) {
        int row0 = rowBase + wrow + i * 16 + quad * 4;
#pragma unroll
        for (int j = 0; j < 4; ++j) {
            int col = colBase + wcol + j * 16 + lo;
            if (col >= N) continue;
#pragma unroll
            for (int r = 0; r < 4; ++r) {
                int row = row0 + r;
                if (row < M) C[(size_t)row * N + col] = acc[i][j][r];
            }
        }
    }
}

// transpose + fp32->bf16: WT[n*K+k] = bf16(W[k*N+n])
__global__ void wt_cvt_transpose(const float* __restrict__ W, ushort_t* __restrict__ WT,
                                 int K, int N) {
    int i = blockIdx.x * blockDim.x + threadIdx.x;
    if (i >= N * K) return;
    int n = i / K, k = i - n * K;
    WT[i] = f2b(W[(size_t)k * N + n]);
}

// ---------------- fp32 tiled GEMM (FC head) ----------------
__global__ __launch_bounds__(256) void gemm_tile(const float* __restrict__ A,
                                                 const float* __restrict__ B,
                                                 float* __restrict__ C,
                                                 int M, int N, int K) {
    __shared__ float As[16][64];
    __shared__ float Bs[16][64];
    const int t = threadIdx.x;
    const int tx = t & 15, ty = t >> 4;
    const int rowBase = blockIdx.y * 64;
    const int colBase = blockIdx.x * 64;
    float acc[4][4] = {};
    for (int k0 = 0; k0 < K; k0 += 16) {
#pragma unroll
        for (int i = 0; i < 4; ++i) {
            int idx = t + i * 256;
            int row = idx >> 4, kk = idx & 15;
            int gr = rowBase + row;
            As[kk][row] = (gr < M) ? A[(size_t)gr * K + k0 + kk] : 0.f;
        }
#pragma unroll
        for (int i = 0; i < 4; ++i) {
            int idx = t + i * 256;
            int kk = idx >> 6, col = idx & 63;
            int gc = colBase + col;
            Bs[kk][col] = (gc < N) ? B[(size_t)(k0 + kk) * N + gc] : 0.f;
        }
        __syncthreads();
#pragma unroll
        for (int kk = 0; kk < 16; ++kk) {
            float a[4], b[4];
#pragma unroll
            for (int i = 0; i < 4; ++i) a[i] = As[kk][ty * 4 + i];
#pragma unroll
            for (int j = 0; j < 4; ++j) b[j] = Bs[kk][tx * 4 + j];
#pragma unroll
            for (int i = 0; i < 4; ++i)
#pragma unroll
                for (int j = 0; j < 4; ++j) acc[i][j] = fmaf(a[i], b[j], acc[i][j]);
        }
        __syncthreads();
    }
#pragma unroll
    for (int i = 0; i < 4; ++i) {
        int gr = rowBase + ty * 4 + i;
        if (gr >= M) continue;
#pragma unroll
        for (int j = 0; j < 4; ++j) {
            int gc = colBase + tx * 4 + j;
            if (gc < N) C[(size_t)gr * N + gc] = acc[i][j];
        }
    }
}

// ---------------- CSR construction ----------------
__global__ void hist_deg(const int* __restrict__ dst, int* __restrict__ cnt) {
    int e = blockIdx.x * blockDim.x + threadIdx.x;
    if (e < N_EDGES) atomicAdd(cnt + dst[e], 1);
}

__global__ void compute_dinv(const int* __restrict__ cnt, float* __restrict__ dinv) {
    int v = blockIdx.x * blockDim.x + threadIdx.x;
    if (v < N_NODES) dinv[v] = rsqrtf((float)cnt[v] + 1.0f);  // +1 self-loop
}

__global__ __launch_bounds__(256) void scan_rowptr(const int* __restrict__ cnt,
                                                   int* __restrict__ rowptr) {
    __shared__ int sums[256];
    const int t = threadIdx.x;
    const int CH = (N_NODES + 255) / 256;
    const int base = t * CH;
    int s = 0;
    for (int i = 0; i < CH; ++i) {
        int v = base + i;
        if (v < N_NODES) s += cnt[v];
    }
    sums[t] = s;
    __syncthreads();
    for (int off = 1; off < 256; off <<= 1) {
        int y = (t >= off) ? sums[t - off] : 0;
        __syncthreads();
        sums[t] += y;
        __syncthreads();
    }
    int run = sums[t] - s;
    for (int i = 0; i < CH; ++i) {
        int v = base + i;
        if (v < N_NODES) {
            rowptr[v] = run;
            run += cnt[v];
        }
    }
    if (t == 255) rowptr[N_NODES] = run;
}

__global__ void fill_csr(const int* __restrict__ src, const int* __restrict__ dst,
                         const int* __restrict__ rowptr, int* __restrict__ cursor,
                         int* __restrict__ col) {
    int e = blockIdx.x * blockDim.x + threadIdx.x;
    if (e < N_EDGES) {
        int d = dst[e];
        int p = rowptr[d] + atomicAdd(cursor + d, 1);
        col[p] = src[e];
    }
}

// ---------------- gather-aggregate kernels ----------------
// shared body: acc = sum_j coef*H[col[j]] + self + bias, relu'd; 1 block/node
__device__ __forceinline__ float4 agg_node(const float* __restrict__ H,
                                           const int* __restrict__ rowptr,
                                           const int* __restrict__ col,
                                           const float* __restrict__ dinv,
                                           const float* __restrict__ bias,
                                           int v, int f) {
    const int beg = rowptr[v], end = rowptr[v + 1];
    const float dv = dinv[v];
    float4 acc = {0.f, 0.f, 0.f, 0.f};
    int j = beg;
    for (; j + 1 < end; j += 2) {
        int s0 = col[j], s1 = col[j + 1];
        float c0 = dinv[s0] * dv, c1 = dinv[s1] * dv;
        float4 h0 = *(const float4*)(H + (size_t)s0 * D_H + f);
        float4 h1 = *(const float4*)(H + (size_t)s1 * D_H + f);
        acc.x += h0.x * c0 + h1.x * c1;
        acc.y += h0.y * c0 + h1.y * c1;
        acc.z += h0.z * c0 + h1.z * c1;
        acc.w += h0.w * c0 + h1.w * c1;
    }
    if (j < end) {
        int s0 = col[j];
        float c0 = dinv[s0] * dv;
        float4 h0 = *(const float4*)(H + (size_t)s0 * D_H + f);
        acc.x += h0.x * c0;
        acc.y += h0.y * c0;
        acc.z += h0.z * c0;
        acc.w += h0.w * c0;
    }
    const float sl = dv * dv;
    float4 hv = *(const float4*)(H + (size_t)v * D_H + f);
    float4 b = *(const float4*)(bias + f);
    float4 r;
    r.x = fmaxf(acc.x + hv.x * sl + b.x, 0.f);
    r.y = fmaxf(acc.y + hv.y * sl + b.y, 0.f);
    r.z = fmaxf(acc.z + hv.z * sl + b.z, 0.f);
    r.w = fmaxf(acc.w + hv.w * sl + b.w, 0.f);
    return r;
}

// conv1 aggregation -> bf16 h1 (feeds conv2 MFMA GEMM)
__global__ __launch_bounds__(128) void gather_agg_relu_bf16(const float* __restrict__ H,
                                                            const int* __restrict__ rowptr,
                                                            const int* __restrict__ col,
                                                            const float* __restrict__ dinv,
                                                            const float* __restrict__ bias,
                                                            ushort_t* __restrict__ out) {
    const int v = blockIdx.x;
    const int f = threadIdx.x * 4;
    float4 r = agg_node(H, rowptr, col, dinv, bias, v, f);
    ushort4 o = {f2b(r.x), f2b(r.y), f2b(r.z), f2b(r.w)};
    *(ushort4*)(out + (size_t)v * D_H + f) = o;
}

// conv2 aggregation fused with global max pool (values >=0, gbuf init 0)
__global__ __launch_bounds__(128) void gather_agg_pool(const float* __restrict__ H,
                                                       const int* __restrict__ rowptr,
                                                       const int* __restrict__ col,
                                                       const float* __restrict__ dinv,
                                                       const float* __restrict__ bias,
                                                       const int* __restrict__ batch,
                                                       float* __restrict__ gbuf) {
    const int v = blockIdx.x;
    const int f = threadIdx.x * 4;
    float4 r = agg_node(H, rowptr, col, dinv, bias, v, f);
    int gr = batch[v];
    int* o = (int*)(gbuf + (size_t)gr * D_H + f);
    atomicMax(o + 0, __float_as_int(r.x));
    atomicMax(o + 1, __float_as_int(r.y));
    atomicMax(o + 2, __float_as_int(r.z));
    atomicMax(o + 3, __float_as_int(r.w));
}

__global__ void bias_relu(float* __restrict__ x, const float* __restrict__ b, int total, int N) {
    int i = blockIdx.x * blockDim.x + threadIdx.x;
    if (i < total) x[i] = fmaxf(x[i] + b[i % N], 0.f);
}

__global__ void bn_sigmoid(const float* __restrict__ logits, const float* __restrict__ b2,
                           const float* __restrict__ gamma, const float* __restrict__ beta,
                           float* __restrict__ out) {
    int i = blockIdx.x * blockDim.x + threadIdx.x;
    if (i >= N_GRAPHS * OUT_DIMS) return;
    int c = i % OUT_DIMS;
    const float s = 0.9999950000374997f;  // 1/sqrt(1+1e-5)
    float z = (logits[i] + b2[c]) * (gamma[c] * s) + beta[c];
    out[i] = 1.f / (1.f + expf(-z));
}

extern "C" void kernel_launch(void* const* d_in, const int* in_sizes, int n_in,
                              void* d_out, int out_size, void* d_ws, size_t ws_size,
                              hipStream_t stream) {
    const float* x     = (const float*)d_in[0];
    const int*   ei    = (const int*)d_in[1];    // int64 in reference -> int32 on device
    const int*   batch = (const int*)d_in[2];
    const float* Wg1   = (const float*)d_in[3];
    const float* bg1   = (const float*)d_in[4];
    const float* Wg2   = (const float*)d_in[5];
    const float* bg2   = (const float*)d_in[6];
    const float* W1    = (const float*)d_in[7];
    const float* b1    = (const float*)d_in[8];
    const float* W2    = (const float*)d_in[9];
    const float* b2    = (const float*)d_in[10];
    const float* gamma = (const float*)d_in[11];
    const float* beta  = (const float*)d_in[12];
    const int* src = ei;
    const int* dst = ei + N_EDGES;
    float* out = (float*)d_out;

    // workspace layout (all 16B-aligned)
    float*    bufA   = (float*)d_ws;                           // [N_NODES, D_H] fp32
    ushort_t* h1b    = (ushort_t*)(bufA + (size_t)N_NODES * D_H);  // [N_NODES, D_H] bf16
    ushort_t* w1t    = h1b + (size_t)N_NODES * D_H;            // [D_H, D_IN] bf16 (Wg1^T)
    ushort_t* w2t    = w1t + (size_t)D_H * D_IN;               // [D_H, D_H] bf16 (Wg2^T)
    float*    dinv   = (float*)(w2t + (size_t)D_H * D_H);      // [N_NODES]
    float*    gbuf   = dinv + N_NODES;                         // [N_GRAPHS, D_H]
    float*    fc1o   = gbuf + N_GRAPHS * D_H;                  // [N_GRAPHS, D_FC]
    float*    logits = fc1o + N_GRAPHS * D_FC;                 // [N_GRAPHS, OUT_DIMS]
    int*      cnt    = (int*)(logits + N_GRAPHS * OUT_DIMS);   // [N_NODES]
    int*      rowptr = cnt + N_NODES;                          // [N_NODES+1]
    int*      cursor = rowptr + N_NODES + 1;                   // [N_NODES]
    int*      colidx = cursor + N_NODES;                       // [N_EDGES]

    // ---- CSR build (by dst) + dinv + weight transpose/convert ----
    hipMemsetAsync(cnt, 0, N_NODES * sizeof(int), stream);
    hipMemsetAsync(cursor, 0, N_NODES * sizeof(int), stream);
    hipMemsetAsync(gbuf, 0, N_GRAPHS * D_H * sizeof(float), stream);
    hist_deg<<<(N_EDGES + 255) / 256, 256, 0, stream>>>(dst, cnt);
    compute_dinv<<<(N_NODES + 255) / 256, 256, 0, stream>>>(cnt, dinv);
    scan_rowptr<<<1, 256, 0, stream>>>(cnt, rowptr);
    fill_csr<<<(N_EDGES + 255) / 256, 256, 0, stream>>>(src, dst, rowptr, cursor, colidx);
    wt_cvt_transpose<<<(D_H * D_IN + 255) / 256, 256, 0, stream>>>(Wg1, w1t, D_IN, D_H);
    wt_cvt_transpose<<<(D_H * D_H + 255) / 256, 256, 0, stream>>>(Wg2, w2t, D_H, D_H);

    dim3 gconv((D_H + 127) / 128, (N_NODES + 127) / 128);  // (4, 157)

    // conv1: bufA = x @ Wg1 (bf16 MFMA, inline cvt of A) ; gather+relu -> h1b (bf16)
    mfma_gemm<true><<<gconv, 256, 0, stream>>>(x, w1t, bufA, N_NODES, D_H, D_IN);
    gather_agg_relu_bf16<<<N_NODES, 128, 0, stream>>>(bufA, rowptr, colidx, dinv, bg1, h1b);

    // conv2: bufA = h1b @ Wg2 ; gather + relu + fused max-pool -> gbuf
    mfma_gemm<false><<<gconv, 256, 0, stream>>>(h1b, w2t, bufA, N_NODES, D_H, D_H);
    gather_agg_pool<<<N_NODES, 128, 0, stream>>>(bufA, rowptr, colidx, dinv, bg2, batch, gbuf);

    // fc1: [64,512]@[512,1024] + b1, relu
    dim3 gfc1((D_FC + 63) / 64, (N_GRAPHS + 63) / 64);
    gemm_tile<<<gfc1, 256, 0, stream>>>(gbuf, W1, fc1o, N_GRAPHS, D_FC, D_H);
    bias_relu<<<(N_GRAPHS * D_FC + 255) / 256, 256, 0, stream>>>(fc1o, b1, N_GRAPHS * D_FC, D_FC);

    // fc2: [64,1024]@[1024,5000] -> logits ; BN + sigmoid -> out
    dim3 gfc2((OUT_DIMS + 63) / 64, (N_GRAPHS + 63) / 64);
    gemm_tile<<<gfc2, 256, 0, stream>>>(fc1o, W2, logits, N_GRAPHS, OUT_DIMS, D_FC);
    bn_sigmoid<<<(N_GRAPHS * OUT_DIMS + 255) / 256, 256, 0, stream>>>(logits, b2, gamma, beta, out);
}